// Round 6
// baseline (625.210 us; speedup 1.0000x reference)
//
#include <hip/hip_runtime.h>
#include <hip/hip_fp16.h>
#include <hip/hip_cooperative_groups.h>
namespace cg = cooperative_groups;

#define F_IN 128
#define F_OUT 32
#define BSH 7           // 128 nodes per bucket
#define BMSK 127
#define MAXNB 2048      // supports N up to 262144

// =================== Cooperative front-end ===============================
// grid = 256 blocks x 256 threads (co-resident on 256 CUs).
// Phase A: block0 specnorm, blocks1..255 bucket hist -> M[p][b]
// Phase B: per-bucket exclusive scan over partitions -> Mex[b][p], total[b]
// Phase C: block0 scan of totals -> base[NB+1]
// Phase D: partition scatter -> staging (LDS cursors, no global atomics)
// Phase E: per-bucket degree -> dis
__global__ __launch_bounds__(256) void k_coop(
    const float* __restrict__ W, const float* __restrict__ u, float* __restrict__ Wsc,
    const int* __restrict__ ei, int* __restrict__ M, int* __restrict__ Mex,
    int* __restrict__ total, int* __restrict__ base,
    unsigned* __restrict__ staging, float* __restrict__ dis,
    int E_, int Nn, int NB) {
    cg::grid_group grid = cg::this_grid();
    __shared__ int smi[MAXNB];
    __shared__ int sd[256];
    __shared__ float sv[F_IN];
    __shared__ float sr[F_IN];
    __shared__ float ssc;
    int p = blockIdx.x, t = threadIdx.x;
    int epb = (E_ + 254) / 255;

    // ---------------- Phase A ----------------
    if (p == 0) {
        // spectral norm: sigma = ||W v||, v = normalize(W^T u)
        if (t < F_IN) {
            float acc = 0.f;
            for (int i = 0; i < F_OUT; ++i) acc += W[i * F_IN + t] * u[i];
            sv[t] = acc; sr[t] = acc * acc;
        }
        __syncthreads();
        if (t == 0) {
            float s = 0.f;
            for (int i = 0; i < F_IN; ++i) s += sr[i];
            ssc = 1.0f / fmaxf(sqrtf(s), 1e-12f);
        }
        __syncthreads();
        if (t < F_IN) sv[t] *= ssc;
        __syncthreads();
        if (t < F_OUT) {
            float a2 = 0.f;
            for (int j = 0; j < F_IN; ++j) a2 += W[t * F_IN + j] * sv[j];
            sr[t] = a2 * a2;
        }
        __syncthreads();
        if (t == 0) {
            float s = 0.f;
            for (int i = 0; i < F_OUT; ++i) s += sr[i];
            ssc = 1.0f / fmaxf(sqrtf(s), 1e-30f);  // 1/sigma
        }
        __syncthreads();
        if (t < F_IN) {
            float is = ssc;
            for (int i = 0; i < F_OUT; ++i) Wsc[i * F_IN + t] = W[i * F_IN + t] * is;
        }
        for (int b = t; b < NB; b += 256) M[b] = 0;  // M[0][b] = 0 (block0 has no chunk)
    } else {
        for (int b = t; b < NB; b += 256) smi[b] = 0;
        __syncthreads();
        int e0 = (p - 1) * epb, e1 = min(e0 + epb, E_);
        const int* col = ei + E_;
        for (int e = e0 + t; e < e1; e += 256)
            atomicAdd(&smi[col[e] >> BSH], 1);          // LDS atomic
        __syncthreads();
        int* Mp = M + (size_t)p * MAXNB;
        for (int b = t; b < NB; b += 256) Mp[b] = smi[b];  // coalesced private row
    }
    grid.sync();

    // ---------------- Phase B: scan over partitions for each bucket -------
    for (int b = p; b < NB; b += 256) {
        int v = M[(size_t)t * MAXNB + b];
        sd[t] = v;
        __syncthreads();
        for (int o = 1; o < 256; o <<= 1) {
            int uu = (t >= o) ? sd[t - o] : 0;
            __syncthreads();
            sd[t] += uu;
            __syncthreads();
        }
        Mex[(size_t)b * 256 + t] = sd[t] - v;   // coalesced write
        if (t == 255) total[b] = sd[255];
        __syncthreads();
    }
    grid.sync();

    // ---------------- Phase C: bucket-total scan (block 0) ----------------
    if (p == 0) {
        int C = (NB + 255) / 256;
        int i0 = t * C, i1 = min(i0 + C, NB);
        int s = 0;
        for (int i = i0; i < i1; ++i) s += total[i];
        int tsum = s;
        sd[t] = s;
        __syncthreads();
        for (int o = 1; o < 256; o <<= 1) {
            int uu = (t >= o) ? sd[t - o] : 0;
            __syncthreads();
            sd[t] += uu;
            __syncthreads();
        }
        int run = sd[t] - tsum;
        for (int i = i0; i < i1; ++i) { base[i] = run; run += total[i]; }
        if (t == 255) base[NB] = sd[255];  // == E
    }
    grid.sync();

    // ---------------- Phase D: partition scatter --------------------------
    if (p > 0) {
        for (int b = t; b < NB; b += 256) smi[b] = base[b] + Mex[(size_t)b * 256 + p];
        __syncthreads();
        int e0 = (p - 1) * epb, e1 = min(e0 + epb, E_);
        for (int e = e0 + t; e < e1; e += 256) {
            int c = ei[E_ + e];
            int r = ei[e];
            int pos = atomicAdd(&smi[c >> BSH], 1);   // LDS atomic (block-private)
            staging[pos] = ((unsigned)r << BSH) | (unsigned)(c & BMSK);
        }
    }
    grid.sync();

    // ---------------- Phase E: per-bucket degree -> dis -------------------
    for (int b = p; b < NB; b += 256) {
        if (t < 128) smi[t] = 0;
        __syncthreads();
        int s0 = base[b], s1 = base[b + 1];
        for (int jj = s0 + t; jj < s1; jj += 256)
            atomicAdd(&smi[staging[jj] & BMSK], 1);    // LDS atomic
        __syncthreads();
        int nb0 = b << BSH;
        if (t < 128 && nb0 + t < Nn) dis[nb0 + t] = rsqrtf((float)smi[t] + 1.0f);
        __syncthreads();
    }
}

// =================== K1: xwh(f16) = (x @ Wsc^T) * dis[row] ===============
__global__ __launch_bounds__(256) void k1_xw(const float* __restrict__ x,
                                             const float* __restrict__ Wsc,
                                             const float* __restrict__ dis,
                                             __half* __restrict__ xwh, int Nn) {
    __shared__ float xs[128 * 65];
    __shared__ float wt[128 * 32];
    int t = threadIdx.x;
    int rbase = blockIdx.x * 128;

    {   // stage W transposed
        int f = t >> 3;
        int kb = 16 * (t & 7);
        const float4* wrow = (const float4*)(Wsc + (size_t)f * F_IN + kb);
#pragma unroll
        for (int j = 0; j < 4; ++j) {
            float4 w = wrow[j];
            int k = kb + 4 * j;
            wt[(k + 0) * 32 + f] = w.x;
            wt[(k + 1) * 32 + f] = w.y;
            wt[(k + 2) * 32 + f] = w.z;
            wt[(k + 3) * 32 + f] = w.w;
        }
    }

    int r0 = (t >> 3) * 4;
    int f0 = (t & 7) * 4;
    float4 acc0 = {0, 0, 0, 0}, acc1 = {0, 0, 0, 0};
    float4 acc2 = {0, 0, 0, 0}, acc3 = {0, 0, 0, 0};
    const float4* wt4 = (const float4*)wt;
    int fq = f0 >> 2;

    for (int kc = 0; kc < 2; ++kc) {
        __syncthreads();
        {
            int rr = t >> 4;
            int k0 = 4 * (t & 15);
#pragma unroll
            for (int pi = 0; pi < 8; ++pi) {
                int r = pi * 16 + rr;
                int grow = rbase + r;
                if (grow >= Nn) grow = Nn - 1;
                float4 v = *(const float4*)(x + (size_t)grow * F_IN + kc * 64 + k0);
                xs[r * 65 + k0 + 0] = v.x;
                xs[r * 65 + k0 + 1] = v.y;
                xs[r * 65 + k0 + 2] = v.z;
                xs[r * 65 + k0 + 3] = v.w;
            }
        }
        __syncthreads();
#pragma unroll 4
        for (int kk = 0; kk < 64; ++kk) {
            int k = kc * 64 + kk;
            float4 w = wt4[k * 8 + fq];
            float x0 = xs[(r0 + 0) * 65 + kk];
            float x1 = xs[(r0 + 1) * 65 + kk];
            float x2 = xs[(r0 + 2) * 65 + kk];
            float x3 = xs[(r0 + 3) * 65 + kk];
            acc0.x += x0 * w.x; acc0.y += x0 * w.y; acc0.z += x0 * w.z; acc0.w += x0 * w.w;
            acc1.x += x1 * w.x; acc1.y += x1 * w.y; acc1.z += x1 * w.z; acc1.w += x1 * w.w;
            acc2.x += x2 * w.x; acc2.y += x2 * w.y; acc2.z += x2 * w.z; acc2.w += x2 * w.w;
            acc3.x += x3 * w.x; acc3.y += x3 * w.y; acc3.z += x3 * w.z; acc3.w += x3 * w.w;
        }
    }
    int g0 = rbase + r0;
#pragma unroll
    for (int q = 0; q < 4; ++q) {
        int g = g0 + q;
        if (g < Nn) {
            float d = dis[g];
            float4 a = (q == 0) ? acc0 : (q == 1) ? acc1 : (q == 2) ? acc2 : acc3;
            ushort4 s;
            s.x = __half_as_ushort(__float2half(a.x * d));
            s.y = __half_as_ushort(__float2half(a.y * d));
            s.z = __half_as_ushort(__float2half(a.z * d));
            s.w = __half_as_ushort(__float2half(a.w * d));
            *(ushort4*)(xwh + (size_t)g * F_OUT + f0) = s;
        }
    }
}

// =================== Fused gather: LDS accumulators, no esr ==============
// One block per 128-node bucket. 16 groups x 16 lanes; half2 row loads.
__global__ __launch_bounds__(256) void k_gather(const unsigned* __restrict__ staging,
        const int* __restrict__ base, const __half* __restrict__ xwh,
        const float* __restrict__ dis, const float* __restrict__ bias,
        const float* __restrict__ pa, float* __restrict__ out, int Nn) {
    __shared__ float acc[128 * 32];   // 16 KB
    int b = blockIdx.x, t = threadIdx.x;
    int nb0 = b << BSH;
    int nc = min(128, Nn - nb0);
    for (int i = t; i < 128 * 32; i += 256) acc[i] = 0.f;
    __syncthreads();
    int s0 = base[b], s1 = base[b + 1];
    int g = t >> 4, f2 = t & 15;
    int j = s0 + g;
    for (; j + 16 < s1; j += 32) {
        unsigned v0 = staging[j];
        unsigned v1 = staging[j + 16];
        int c0 = v0 & BMSK, r0 = (int)(v0 >> BSH);
        int c1 = v1 & BMSK, r1 = (int)(v1 >> BSH);
        float2 a0 = __half22float2(*((const __half2*)(xwh + (size_t)r0 * F_OUT) + f2));
        float2 a1 = __half22float2(*((const __half2*)(xwh + (size_t)r1 * F_OUT) + f2));
        atomicAdd(&acc[c0 * 32 + 2 * f2],     a0.x);
        atomicAdd(&acc[c0 * 32 + 2 * f2 + 1], a0.y);
        atomicAdd(&acc[c1 * 32 + 2 * f2],     a1.x);
        atomicAdd(&acc[c1 * 32 + 2 * f2 + 1], a1.y);
    }
    if (j < s1) {
        unsigned v0 = staging[j];
        int c0 = v0 & BMSK, r0 = (int)(v0 >> BSH);
        float2 a0 = __half22float2(*((const __half2*)(xwh + (size_t)r0 * F_OUT) + f2));
        atomicAdd(&acc[c0 * 32 + 2 * f2],     a0.x);
        atomicAdd(&acc[c0 * 32 + 2 * f2 + 1], a0.y);
    }
    __syncthreads();
    float aslope = pa[0];
    for (int idx = t; idx < nc * 32; idx += 256) {
        int node = nb0 + (idx >> 5);
        int f = idx & 31;
        float dc = dis[node];
        float s = __half2float(xwh[(size_t)node * F_OUT + f]);
        float v = (acc[idx] + s) * dc + bias[f];
        out[(size_t)node * F_OUT + f] = (v >= 0.f) ? v : aslope * v;
    }
}

// =================== Fallback path (small ws): atomic scatter ============
__global__ void k0_specnorm(const float* __restrict__ W, const float* __restrict__ u,
                            float* __restrict__ Wsc) {
    __shared__ float v[F_IN];
    __shared__ float red[F_IN];
    __shared__ float scal;
    int t = threadIdx.x;
    float acc = 0.f;
    for (int i = 0; i < F_OUT; ++i) acc += W[i * F_IN + t] * u[i];
    v[t] = acc; red[t] = acc * acc;
    __syncthreads();
    if (t == 0) {
        float s = 0.f;
        for (int i = 0; i < F_IN; ++i) s += red[i];
        scal = 1.0f / fmaxf(sqrtf(s), 1e-12f);
    }
    __syncthreads();
    v[t] *= scal;
    __syncthreads();
    if (t < F_OUT) {
        float a2 = 0.f;
        for (int j = 0; j < F_IN; ++j) a2 += W[t * F_IN + j] * v[j];
        red[t] = a2 * a2;
    }
    __syncthreads();
    if (t == 0) {
        float s = 0.f;
        for (int i = 0; i < F_OUT; ++i) s += red[i];
        scal = 1.0f / fmaxf(sqrtf(s), 1e-30f);
    }
    __syncthreads();
    float is = scal;
    for (int i = 0; i < F_OUT; ++i)
        Wsc[i * F_IN + t] = W[i * F_IN + t] * is;
}

__global__ void k1_xw_f32(const float* __restrict__ x, const float* __restrict__ Wsc,
                          const float* __restrict__ dis, float* __restrict__ xw, int Nn) {
    int id = blockIdx.x * blockDim.x + threadIdx.x;
    if (id >= Nn * F_OUT) return;
    int r = id >> 5, f = id & 31;
    const float4* x4 = (const float4*)(x + (size_t)r * F_IN);
    const float4* w4 = (const float4*)(Wsc + (size_t)f * F_IN);
    float acc = 0.f;
#pragma unroll
    for (int k = 0; k < F_IN / 4; ++k) {
        float4 a = x4[k];
        float4 b = w4[k];
        acc += a.x * b.x + a.y * b.y + a.z * b.z + a.w * b.w;
    }
    xw[id] = acc * dis[r];
}

__global__ void k2_deg(const int* __restrict__ col, int* __restrict__ cnt, int E_) {
    int e = blockIdx.x * blockDim.x + threadIdx.x;
    if (e < E_) atomicAdd(&cnt[col[e]], 1);
}

__global__ void k3_dis(const int* __restrict__ cnt, float* __restrict__ dis, int Nn) {
    int i = blockIdx.x * blockDim.x + threadIdx.x;
    if (i < Nn) dis[i] = rsqrtf((float)cnt[i] + 1.0f);
}

__global__ void k4_scatter(const int* __restrict__ ei, const float* __restrict__ xws,
                           const float* __restrict__ dis, float* __restrict__ out, int E_) {
    int id = blockIdx.x * blockDim.x + threadIdx.x;
    if (id >= E_ * F_OUT) return;
    int e = id >> 5, f = id & 31;
    int r = ei[e];
    int c = ei[E_ + e];
    atomicAdd(&out[(size_t)c * F_OUT + f], xws[(size_t)r * F_OUT + f] * dis[c]);
}

__global__ void k5_epi(const float* __restrict__ xws, const float* __restrict__ dis,
                       const float* __restrict__ bias, const float* __restrict__ pa,
                       float* __restrict__ out, int Nn) {
    int id = blockIdx.x * blockDim.x + threadIdx.x;
    if (id >= Nn * F_OUT) return;
    int i = id >> 5, f = id & 31;
    float d = dis[i];
    float v = out[id] + xws[id] * d + bias[f];
    float a = pa[0];
    out[id] = (v >= 0.f) ? v : a * v;
}

extern "C" void kernel_launch(void* const* d_in, const int* in_sizes, int n_in,
                              void* d_out, int out_size, void* d_ws, size_t ws_size,
                              hipStream_t stream) {
    const float* x    = (const float*)d_in[0];
    const int*   ei   = (const int*)d_in[1];   // [2,E]: row = ei[0:E], col = ei[E:2E]
    const float* W    = (const float*)d_in[2];
    const float* bias = (const float*)d_in[3];
    const float* pa   = (const float*)d_in[4];
    const float* u    = (const float*)d_in[5];

    int Nn = in_sizes[0] / F_IN;   // 100000
    int E_ = in_sizes[1] / 2;      // 1600000
    float* out = (float*)d_out;

    int NB = (Nn + BMSK) >> BSH;   // 128-node buckets

    // ws layout (4B words):
    // xwh [N*16] | Wsc [4096] | dis [N] | M [256*MAXNB] | Mex [NB*256] |
    // total [NB] | base [NB+1] | staging [E]
    size_t o = 0;
    __half*   xwh     = (__half*)d_ws;       o += (size_t)Nn * (F_OUT / 2);
    float*    Wsc     = (float*)d_ws + o;    o += F_OUT * F_IN;
    float*    dis     = (float*)d_ws + o;    o += Nn;
    int*      M       = (int*)d_ws + o;      o += (size_t)256 * MAXNB;
    int*      Mex     = (int*)d_ws + o;      o += (size_t)NB * 256;
    int*      total   = (int*)d_ws + o;      o += NB;
    int*      base    = (int*)d_ws + o;      o += NB + 1;
    unsigned* staging = (unsigned*)d_ws + o; o += E_;
    bool big_ws = (ws_size >= o * sizeof(float)) && (NB <= MAXNB);

    if (big_ws) {
        void* args[] = {(void*)&W, (void*)&u, (void*)&Wsc, (void*)&ei,
                        (void*)&M, (void*)&Mex, (void*)&total, (void*)&base,
                        (void*)&staging, (void*)&dis,
                        (void*)&E_, (void*)&Nn, (void*)&NB};
        hipLaunchCooperativeKernel((const void*)k_coop, dim3(256), dim3(256),
                                   args, 0, stream);
        k1_xw<<<(Nn + 127) / 128, 256, 0, stream>>>(x, Wsc, dis, xwh, Nn);
        k_gather<<<NB, 256, 0, stream>>>(staging, base, xwh, dis, bias, pa, out, Nn);
    } else {
        // fp32 fallback: xw | Wsc | dis | deg
        size_t o2 = 0;
        float* xw2  = (float*)d_ws;       o2 += (size_t)Nn * F_OUT;
        float* Wsc2 = (float*)d_ws + o2;  o2 += F_OUT * F_IN;
        float* dis2 = (float*)d_ws + o2;  o2 += Nn;
        int*   deg2 = (int*)d_ws + o2;    o2 += Nn;
        hipMemsetAsync(deg2, 0, (size_t)Nn * sizeof(int), stream);
        hipMemsetAsync(d_out, 0, (size_t)Nn * F_OUT * sizeof(float), stream);
        k0_specnorm<<<1, 128, 0, stream>>>(W, u, Wsc2);
        k2_deg<<<(E_ + 255) / 256, 256, 0, stream>>>(ei + E_, deg2, E_);
        k3_dis<<<(Nn + 255) / 256, 256, 0, stream>>>(deg2, dis2, Nn);
        int nT1 = Nn * F_OUT;
        k1_xw_f32<<<(nT1 + 255) / 256, 256, 0, stream>>>(x, Wsc2, dis2, xw2, Nn);
        int nT4 = E_ * F_OUT;
        k4_scatter<<<(nT4 + 255) / 256, 256, 0, stream>>>(ei, xw2, dis2, out, E_);
        k5_epi<<<(nT1 + 255) / 256, 256, 0, stream>>>(xw2, dis2, bias, pa, out, Nn);
    }
}

// Round 7
// 189.333 us; speedup vs baseline: 3.3022x; 3.3022x over previous
//
#include <hip/hip_runtime.h>
#include <hip/hip_fp16.h>

#define F_IN 128
#define F_OUT 32
#define BSH 8           // 256 nodes per bucket
#define BMSK 255

// =================== L1: k1h = specnorm + hist-slice + matmul ============
// grid = P = ceil(N/128) blocks x 256 threads.
// Phase H: edge-slice bucket histogram -> M[p*NB + b] (coalesced row write)
// Phase S: redundant spectral norm (every block computes 1/sigma)
// Phase M: LDS-tiled matmul -> xwh (f16, NOT dis-scaled)
__global__ __launch_bounds__(256) void k1h(
    const float* __restrict__ x, const float* __restrict__ W,
    const float* __restrict__ u, const int* __restrict__ ei,
    __half* __restrict__ xwh, int* __restrict__ M,
    int Nn, int E_, int NB, int P) {
    __shared__ float xs[128 * 65];   // 33.3 KB
    __shared__ float wt[128 * 32];   // 16 KB
    __shared__ int   smi[512];
    __shared__ float sv[F_IN];
    __shared__ float sr[F_IN];
    __shared__ float ssc;
    int t = threadIdx.x;
    int p = blockIdx.x;

    // ---- Phase H: histogram slice ----
    for (int b = t; b < NB; b += 256) smi[b] = 0;
    __syncthreads();
    int epb = (E_ + P - 1) / P;
    int e0 = p * epb, e1 = min(e0 + epb, E_);
    const int* col = ei + E_;
    for (int e = e0 + t; e < e1; e += 256)
        atomicAdd(&smi[col[e] >> BSH], 1);          // LDS atomic
    __syncthreads();
    for (int b = t; b < NB; b += 256) M[(size_t)p * NB + b] = smi[b];

    // ---- Phase S: spectral norm (redundant per block) ----
    if (t < F_IN) {
        float a = 0.f;
        for (int i = 0; i < F_OUT; ++i) a += W[i * F_IN + t] * u[i];
        sv[t] = a; sr[t] = a * a;
    }
    __syncthreads();
    for (int o = 64; o > 0; o >>= 1) {
        if (t < o) sr[t] += sr[t + o];
        __syncthreads();
    }
    if (t == 0) ssc = 1.0f / fmaxf(sqrtf(sr[0]), 1e-12f);
    __syncthreads();
    if (t < F_IN) sv[t] *= ssc;
    __syncthreads();
    if (t < F_OUT) {
        float a = 0.f;
        for (int j = 0; j < F_IN; ++j) a += W[t * F_IN + j] * sv[j];
        sr[t] = a * a;
    }
    __syncthreads();
    for (int o = 16; o > 0; o >>= 1) {
        if (t < o) sr[t] += sr[t + o];
        __syncthreads();
    }
    if (t == 0) ssc = 1.0f / fmaxf(sqrtf(sr[0]), 1e-30f);  // 1/sigma
    __syncthreads();
    float is = ssc;

    // ---- Phase M: matmul tile ----
    int rbase = p * 128;
    {   // stage W transposed, scaled by 1/sigma
        int f = t >> 3;
        int kb = 16 * (t & 7);
        const float4* wrow = (const float4*)(W + (size_t)f * F_IN + kb);
#pragma unroll
        for (int j = 0; j < 4; ++j) {
            float4 w = wrow[j];
            int k = kb + 4 * j;
            wt[(k + 0) * 32 + f] = w.x * is;
            wt[(k + 1) * 32 + f] = w.y * is;
            wt[(k + 2) * 32 + f] = w.z * is;
            wt[(k + 3) * 32 + f] = w.w * is;
        }
    }

    int r0 = (t >> 3) * 4;
    int f0 = (t & 7) * 4;
    float4 acc0 = {0, 0, 0, 0}, acc1 = {0, 0, 0, 0};
    float4 acc2 = {0, 0, 0, 0}, acc3 = {0, 0, 0, 0};
    const float4* wt4 = (const float4*)wt;
    int fq = f0 >> 2;

    for (int kc = 0; kc < 2; ++kc) {
        __syncthreads();
        {
            int rr = t >> 4;
            int k0 = 4 * (t & 15);
#pragma unroll
            for (int pi = 0; pi < 8; ++pi) {
                int r = pi * 16 + rr;
                int grow = rbase + r;
                if (grow >= Nn) grow = Nn - 1;
                float4 v = *(const float4*)(x + (size_t)grow * F_IN + kc * 64 + k0);
                xs[r * 65 + k0 + 0] = v.x;
                xs[r * 65 + k0 + 1] = v.y;
                xs[r * 65 + k0 + 2] = v.z;
                xs[r * 65 + k0 + 3] = v.w;
            }
        }
        __syncthreads();
#pragma unroll 4
        for (int kk = 0; kk < 64; ++kk) {
            int k = kc * 64 + kk;
            float4 w = wt4[k * 8 + fq];
            float x0 = xs[(r0 + 0) * 65 + kk];
            float x1 = xs[(r0 + 1) * 65 + kk];
            float x2 = xs[(r0 + 2) * 65 + kk];
            float x3 = xs[(r0 + 3) * 65 + kk];
            acc0.x += x0 * w.x; acc0.y += x0 * w.y; acc0.z += x0 * w.z; acc0.w += x0 * w.w;
            acc1.x += x1 * w.x; acc1.y += x1 * w.y; acc1.z += x1 * w.z; acc1.w += x1 * w.w;
            acc2.x += x2 * w.x; acc2.y += x2 * w.y; acc2.z += x2 * w.z; acc2.w += x2 * w.w;
            acc3.x += x3 * w.x; acc3.y += x3 * w.y; acc3.z += x3 * w.z; acc3.w += x3 * w.w;
        }
    }
    int g0 = rbase + r0;
#pragma unroll
    for (int q = 0; q < 4; ++q) {
        int g = g0 + q;
        if (g < Nn) {
            float4 a = (q == 0) ? acc0 : (q == 1) ? acc1 : (q == 2) ? acc2 : acc3;
            ushort4 s;
            s.x = __half_as_ushort(__float2half(a.x));
            s.y = __half_as_ushort(__float2half(a.y));
            s.z = __half_as_ushort(__float2half(a.z));
            s.w = __half_as_ushort(__float2half(a.w));
            *(ushort4*)(xwh + (size_t)g * F_OUT + f0) = s;
        }
    }
}

// ============ L2: k_scanA — per-bucket exclusive scan over partitions =====
// grid = NB blocks. In-place: M[p][b] -> sum_{p'<p} M[p'][b]; total[b] = row sum.
__global__ __launch_bounds__(256) void k_scanA(int* __restrict__ M,
                                               int* __restrict__ total,
                                               int NB, int P) {
    __shared__ int sd[256];
    int b = blockIdx.x, t = threadIdx.x;
    int C = (P + 255) >> 8;   // <= 8
    int vals[8];
    int run = 0;
#pragma unroll 4
    for (int j = 0; j < C; ++j) {
        int p = t * C + j;
        int v = (p < P) ? M[(size_t)p * NB + b] : 0;
        vals[j] = run;          // exclusive within chunk
        run += v;
    }
    int tsum = run;
    sd[t] = tsum;
    __syncthreads();
    for (int o = 1; o < 256; o <<= 1) {
        int u = (t >= o) ? sd[t - o] : 0;
        __syncthreads();
        sd[t] += u;
        __syncthreads();
    }
    int cb = sd[t] - tsum;      // exclusive chunk base
#pragma unroll 4
    for (int j = 0; j < C; ++j) {
        int p = t * C + j;
        if (p < P) M[(size_t)p * NB + b] = cb + vals[j];
    }
    if (t == 255) total[b] = sd[255];
}

// ============ L3: k_scat1 — redundant base-scan + partition scatter =======
// grid = P blocks. Block 0 also publishes base[] for k_sort2.
__global__ __launch_bounds__(256) void k_scat1(
    const int* __restrict__ ei, const int* __restrict__ M,
    const int* __restrict__ total, int* __restrict__ base,
    unsigned* __restrict__ staging, int E_, int NB, int P) {
    __shared__ int scur[512];
    __shared__ int sd[256];
    int p = blockIdx.x, t = threadIdx.x;
    // redundant exclusive scan of total[0..NB)
    int C = (NB + 255) >> 8;   // <= 2
    int vals[2];
    int run = 0;
#pragma unroll
    for (int j = 0; j < 2; ++j) {
        int b = t * C + j;
        int v = (j < C && b < NB) ? total[b] : 0;
        vals[j] = run;
        run += v;
    }
    int tsum = run;
    sd[t] = tsum;
    __syncthreads();
    for (int o = 1; o < 256; o <<= 1) {
        int u = (t >= o) ? sd[t - o] : 0;
        __syncthreads();
        sd[t] += u;
        __syncthreads();
    }
    int cb = sd[t] - tsum;
#pragma unroll
    for (int j = 0; j < 2; ++j) {
        int b = t * C + j;
        if (j < C && b < NB) {
            int sb = cb + vals[j];
            scur[b] = sb + M[(size_t)p * NB + b];
            if (p == 0) base[b] = sb;
        }
    }
    if (p == 0 && t == 255) base[NB] = sd[255];  // == E
    __syncthreads();
    int epb = (E_ + P - 1) / P;
    int e0 = p * epb, e1 = min(e0 + epb, E_);
    const int* col = ei + E_;
    for (int e = e0 + t; e < e1; e += 256) {
        int c = col[e];
        int r = ei[e];
        int pos = atomicAdd(&scur[c >> BSH], 1);   // LDS atomic (block-private)
        staging[pos] = ((unsigned)r << BSH) | (unsigned)(c & BMSK);
    }
}

// ============ L4: k_sort2 — per-bucket sort + deg/dis/cursor ==============
__global__ __launch_bounds__(256) void k_sort2(
    const unsigned* __restrict__ staging, const int* __restrict__ base,
    int* __restrict__ esr, float* __restrict__ dis,
    int* __restrict__ cursor, int Nn, int E_, int NB) {
    __shared__ int hist[256];
    __shared__ int sd[256];
    __shared__ int lcur[256];
    int b = blockIdx.x, t = threadIdx.x;
    int nb0 = b << BSH;
    int nc = min(256, Nn - nb0);
    hist[t] = 0;
    __syncthreads();
    int s0 = base[b], s1 = base[b + 1];
    for (int j = s0 + t; j < s1; j += 256)
        atomicAdd(&hist[staging[j] & BMSK], 1);    // LDS atomic
    __syncthreads();
    int h = hist[t];
    if (t < nc) dis[nb0 + t] = rsqrtf((float)h + 1.0f);
    sd[t] = h;
    __syncthreads();
    for (int o = 1; o < 256; o <<= 1) {
        int u = (t >= o) ? sd[t - o] : 0;
        __syncthreads();
        sd[t] += u;
        __syncthreads();
    }
    int excl = sd[t] - h;
    if (t < nc) cursor[nb0 + t] = s0 + excl;
    if (b == NB - 1 && t == 0) cursor[Nn] = E_;
    lcur[t] = s0 + excl;
    __syncthreads();
    for (int j = s0 + t; j < s1; j += 256) {
        unsigned v = staging[j];
        int pp = atomicAdd(&lcur[v & BMSK], 1);    // LDS atomic
        esr[pp] = (int)(v >> BSH);
    }
}

// ============ L5: gather — register accum, per-edge dis[r] ================
__global__ __launch_bounds__(256) void k_gather(
    const int* __restrict__ esr, const int* __restrict__ cursor,
    const __half* __restrict__ xwh, const float* __restrict__ dis,
    const float* __restrict__ bias, const float* __restrict__ pa,
    float* __restrict__ out, int Nn) {
    int t = threadIdx.x;
    int node = blockIdx.x * 16 + (t >> 4);
    if (node >= Nn) return;
    int f2 = t & 15;  // feature pair 2*f2, 2*f2+1
    int start = cursor[node], end = cursor[node + 1];
    float accx = 0.f, accy = 0.f;
    for (int j0 = start; j0 < end; j0 += 16) {
        int idx = j0 + f2;
        int rf = (idx < end) ? esr[idx] : 0;
        int m = end - j0;
        if (m > 16) m = 16;
        int i = 0;
        for (; i + 4 <= m; i += 4) {
            int r0 = __shfl(rf, i + 0, 16);
            int r1 = __shfl(rf, i + 1, 16);
            int r2 = __shfl(rf, i + 2, 16);
            int r3 = __shfl(rf, i + 3, 16);
            float d0 = dis[r0], d1 = dis[r1], d2 = dis[r2], d3 = dis[r3];
            float2 a0 = __half22float2(*((const __half2*)(xwh + (size_t)r0 * F_OUT) + f2));
            float2 a1 = __half22float2(*((const __half2*)(xwh + (size_t)r1 * F_OUT) + f2));
            float2 a2 = __half22float2(*((const __half2*)(xwh + (size_t)r2 * F_OUT) + f2));
            float2 a3 = __half22float2(*((const __half2*)(xwh + (size_t)r3 * F_OUT) + f2));
            accx += a0.x * d0 + a1.x * d1 + a2.x * d2 + a3.x * d3;
            accy += a0.y * d0 + a1.y * d1 + a2.y * d2 + a3.y * d3;
        }
        for (; i < m; ++i) {
            int r = __shfl(rf, i, 16);
            float d = dis[r];
            float2 a = __half22float2(*((const __half2*)(xwh + (size_t)r * F_OUT) + f2));
            accx += a.x * d;
            accy += a.y * d;
        }
    }
    float dc = dis[node];
    float2 self = __half22float2(*((const __half2*)(xwh + (size_t)node * F_OUT) + f2));
    float2 bi = *((const float2*)bias + f2);
    float a = pa[0];
    float vx = (accx + self.x * dc) * dc + bi.x;
    float vy = (accy + self.y * dc) * dc + bi.y;
    float2 o;
    o.x = (vx >= 0.f) ? vx : a * vx;
    o.y = (vy >= 0.f) ? vy : a * vy;
    *((float2*)(out + (size_t)node * F_OUT) + f2) = o;
}

// =================== Fallback path (small ws): atomic scatter ============
__global__ void k0_specnorm(const float* __restrict__ W, const float* __restrict__ u,
                            float* __restrict__ Wsc) {
    __shared__ float v[F_IN];
    __shared__ float red[F_IN];
    __shared__ float scal;
    int t = threadIdx.x;
    float acc = 0.f;
    for (int i = 0; i < F_OUT; ++i) acc += W[i * F_IN + t] * u[i];
    v[t] = acc; red[t] = acc * acc;
    __syncthreads();
    if (t == 0) {
        float s = 0.f;
        for (int i = 0; i < F_IN; ++i) s += red[i];
        scal = 1.0f / fmaxf(sqrtf(s), 1e-12f);
    }
    __syncthreads();
    v[t] *= scal;
    __syncthreads();
    if (t < F_OUT) {
        float a2 = 0.f;
        for (int j = 0; j < F_IN; ++j) a2 += W[t * F_IN + j] * v[j];
        red[t] = a2 * a2;
    }
    __syncthreads();
    if (t == 0) {
        float s = 0.f;
        for (int i = 0; i < F_OUT; ++i) s += red[i];
        scal = 1.0f / fmaxf(sqrtf(s), 1e-30f);
    }
    __syncthreads();
    float is = scal;
    for (int i = 0; i < F_OUT; ++i)
        Wsc[i * F_IN + t] = W[i * F_IN + t] * is;
}

__global__ void k1_xw_f32(const float* __restrict__ x, const float* __restrict__ Wsc,
                          const float* __restrict__ dis, float* __restrict__ xw, int Nn) {
    int id = blockIdx.x * blockDim.x + threadIdx.x;
    if (id >= Nn * F_OUT) return;
    int r = id >> 5, f = id & 31;
    const float4* x4 = (const float4*)(x + (size_t)r * F_IN);
    const float4* w4 = (const float4*)(Wsc + (size_t)f * F_IN);
    float acc = 0.f;
#pragma unroll
    for (int k = 0; k < F_IN / 4; ++k) {
        float4 a = x4[k];
        float4 b = w4[k];
        acc += a.x * b.x + a.y * b.y + a.z * b.z + a.w * b.w;
    }
    xw[id] = acc * dis[r];
}

__global__ void k2_deg(const int* __restrict__ col, int* __restrict__ cnt, int E_) {
    int e = blockIdx.x * blockDim.x + threadIdx.x;
    if (e < E_) atomicAdd(&cnt[col[e]], 1);
}

__global__ void k3_dis(const int* __restrict__ cnt, float* __restrict__ dis, int Nn) {
    int i = blockIdx.x * blockDim.x + threadIdx.x;
    if (i < Nn) dis[i] = rsqrtf((float)cnt[i] + 1.0f);
}

__global__ void k4_scatter(const int* __restrict__ ei, const float* __restrict__ xws,
                           const float* __restrict__ dis, float* __restrict__ out, int E_) {
    int id = blockIdx.x * blockDim.x + threadIdx.x;
    if (id >= E_ * F_OUT) return;
    int e = id >> 5, f = id & 31;
    int r = ei[e];
    int c = ei[E_ + e];
    atomicAdd(&out[(size_t)c * F_OUT + f], xws[(size_t)r * F_OUT + f] * dis[c]);
}

__global__ void k5_epi(const float* __restrict__ xws, const float* __restrict__ dis,
                       const float* __restrict__ bias, const float* __restrict__ pa,
                       float* __restrict__ out, int Nn) {
    int id = blockIdx.x * blockDim.x + threadIdx.x;
    if (id >= Nn * F_OUT) return;
    int i = id >> 5, f = id & 31;
    float d = dis[i];
    float v = out[id] + xws[id] * d + bias[f];
    float a = pa[0];
    out[id] = (v >= 0.f) ? v : a * v;
}

extern "C" void kernel_launch(void* const* d_in, const int* in_sizes, int n_in,
                              void* d_out, int out_size, void* d_ws, size_t ws_size,
                              hipStream_t stream) {
    const float* x    = (const float*)d_in[0];
    const int*   ei   = (const int*)d_in[1];   // [2,E]: row = ei[0:E], col = ei[E:2E]
    const float* W    = (const float*)d_in[2];
    const float* bias = (const float*)d_in[3];
    const float* pa   = (const float*)d_in[4];
    const float* u    = (const float*)d_in[5];

    int Nn = in_sizes[0] / F_IN;   // 100000
    int E_ = in_sizes[1] / 2;      // 1600000
    float* out = (float*)d_out;

    int NB = (Nn + BMSK) >> BSH;          // 256-node buckets (391)
    int P  = (Nn + 127) / 128;            // partitions = k1h grid (782)

    // ws layout (4B words):
    // xwh [N*16] | dis [N] | cursor [N+1] | M [P*NB] | total [NB] |
    // base [NB+1] | staging [E] | esr [E]
    size_t o = 0;
    __half*   xwh     = (__half*)d_ws;       o += (size_t)Nn * (F_OUT / 2);
    float*    dis     = (float*)d_ws + o;    o += Nn;
    int*      cursor  = (int*)d_ws + o;      o += Nn + 1;
    int*      M       = (int*)d_ws + o;      o += (size_t)P * NB;
    int*      total   = (int*)d_ws + o;      o += NB;
    int*      base    = (int*)d_ws + o;      o += NB + 1;
    unsigned* staging = (unsigned*)d_ws + o; o += E_;
    int*      esr     = (int*)d_ws + o;      o += E_;
    bool big_ws = (ws_size >= o * sizeof(float)) && (NB <= 512) && (P <= 2048);

    if (big_ws) {
        k1h<<<P, 256, 0, stream>>>(x, W, u, ei, xwh, M, Nn, E_, NB, P);
        k_scanA<<<NB, 256, 0, stream>>>(M, total, NB, P);
        k_scat1<<<P, 256, 0, stream>>>(ei, M, total, base, staging, E_, NB, P);
        k_sort2<<<NB, 256, 0, stream>>>(staging, base, esr, dis, cursor, Nn, E_, NB);
        k_gather<<<(Nn + 15) / 16, 256, 0, stream>>>(esr, cursor, xwh, dis, bias, pa, out, Nn);
    } else {
        // fp32 fallback: xw | Wsc | dis | deg
        size_t o2 = 0;
        float* xw2  = (float*)d_ws;       o2 += (size_t)Nn * F_OUT;
        float* Wsc2 = (float*)d_ws + o2;  o2 += F_OUT * F_IN;
        float* dis2 = (float*)d_ws + o2;  o2 += Nn;
        int*   deg2 = (int*)d_ws + o2;    o2 += Nn;
        hipMemsetAsync(deg2, 0, (size_t)Nn * sizeof(int), stream);
        hipMemsetAsync(d_out, 0, (size_t)Nn * F_OUT * sizeof(float), stream);
        k0_specnorm<<<1, 128, 0, stream>>>(W, u, Wsc2);
        k2_deg<<<(E_ + 255) / 256, 256, 0, stream>>>(ei + E_, deg2, E_);
        k3_dis<<<(Nn + 255) / 256, 256, 0, stream>>>(deg2, dis2, Nn);
        int nT1 = Nn * F_OUT;
        k1_xw_f32<<<(nT1 + 255) / 256, 256, 0, stream>>>(x, Wsc2, dis2, xw2, Nn);
        int nT4 = E_ * F_OUT;
        k4_scatter<<<(nT4 + 255) / 256, 256, 0, stream>>>(ei, xw2, dis2, out, E_);
        k5_epi<<<(nT1 + 255) / 256, 256, 0, stream>>>(xw2, dis2, bias, pa, out, Nn);
    }
}